// Round 4
// baseline (276.466 us; speedup 1.0000x reference)
//
#include <hip/hip_runtime.h>
#include <math.h>

// Problem constants
#define BB    64
#define TT    512
#define TWOH  1024
#define WPB   4                  // waves per block (256 threads); 1 row per wave
#define TCB   WPB                // 4 rows per block-chunk
#define NCHUNK (TT / TCB)        // 128 chunk-partials per b
#define KSPLIT 4                 // d-dim split for k_qgemm
#define NP_STRIDE ((TT + 1) * TWOH)  // 513*1024

// native clang vector type (vectorized loads/stores)
typedef float vfloat4 __attribute__((ext_vector_type(4)));

// NOTE (R3 post-mortem): __builtin_nontemporal_store on out_np caused
// post-timing divergence under the harness's re-poison path — no nt stores.
// NOTE (R1/R2 post-mortem): register-resident staging gets de-prefetched by
// the allocator (VGPR 52/56/60) -> DMA staging via global_load_lds.
// NOTE (R3->R4): DMA staging alone changed nothing (82 us, 2.7 TB/s, VGPR 44).
// Per-wave residency ~35k cyc for 16 KB moved => latency-bound, and every
// version capped itself at 16 waves/CU via __launch_bounds__(256,4). This
// version: 1 row/wave, 16.4 KB LDS, __launch_bounds__(256,8) => 32 waves/CU
// ceiling. Diagnostic: if occupancy ~doubles and dur doesn't move, the
// pattern is BW-capped at ~2.7 TB/s and structure is exonerated.

// direct global->LDS DMA, 16B per lane; lds dst is WAVE-UNIFORM base
// (HW adds lane*16), global src is per-lane.
__device__ __forceinline__ void gload_lds16(const float* g, float* l) {
    __builtin_amdgcn_global_load_lds(
        (const __attribute__((address_space(1))) unsigned int*)g,
        (__attribute__((address_space(3))) unsigned int*)l,
        16, 0, 0);
}

// -------------------------------------------------------------------------
// K1: partial GEMM  qpart[k][b][e] = sum_{d in k-slice} h[b,d] * W[d,e]
// grid = (4 e-chunks, 64 b, 4 k-slices) = 1024 blocks -> 4 blocks/CU.
// -------------------------------------------------------------------------
__global__ __launch_bounds__(256) void k_qgemm(const float* __restrict__ h,
                                               const float* __restrict__ W,
                                               float* __restrict__ qpart) {
    const int tid = threadIdx.x;
    const int e   = blockIdx.x * 256 + tid;      // 0..1023
    const int b   = blockIdx.y;                  // 0..63
    const int k   = blockIdx.z;                  // 0..3
    const int d0  = k * (TWOH / KSPLIT);         // 256-wide d slice

    __shared__ float sh[TWOH / KSPLIT];
    sh[tid] = h[b * TWOH + d0 + tid];
    __syncthreads();

    const float* __restrict__ Wp = W + (size_t)d0 * TWOH + e;
    float acc = 0.f;
    #pragma unroll 16
    for (int d = 0; d < TWOH / KSPLIT; ++d)
        acc = fmaf(sh[d], Wp[(size_t)d * TWOH], acc);

    qpart[((size_t)k * BB + b) * TWOH + e] = acc;
}

// -------------------------------------------------------------------------
// K1b: q[b][e] = sum_k qpart[k][b][e]. Removes the 4-way partial-sum loads
// from the hot kernel (q read drops 16 KB -> 4 KB per scores-block).
// grid = 64 blocks, 256 threads, thread owns one float4.
// -------------------------------------------------------------------------
__global__ __launch_bounds__(256) void k_qreduce(const float* __restrict__ qpart,
                                                 float* __restrict__ q) {
    const int b   = blockIdx.x;
    const int tid = threadIdx.x;
    const vfloat4* __restrict__ qp = (const vfloat4*)qpart;
    const vfloat4 s = qp[(0 * BB + b) * 256 + tid]
                    + qp[(1 * BB + b) * 256 + tid]
                    + qp[(2 * BB + b) * 256 + tid]
                    + qp[(3 * BB + b) * 256 + tid];
    ((vfloat4*)(q + (size_t)b * TWOH))[tid] = s;
}

// -------------------------------------------------------------------------
// K2: occupancy-first. Each wave owns ONE t-row:
//   4x global_load_lds (row -> wave-private 4KB LDS) | 4x q float4 loads
//   -> vmcnt(0) (wave-local, no barrier) -> ds_read row: copy-store to
//   out_np + dot partials -> butterfly -> score to LDS -> ONE barrier ->
//   block softmax over 4 scores -> weighted combine of 4 LDS rows ->
//   one 4-row partial (M,L,o) per block.
// LDS 16.4 KB, VGPR target <=64 -> __launch_bounds__(256,8): 8 blocks/CU,
// 32 waves/CU. grid = (NCHUNK=128, 64 b) = 8192 blocks.
// -------------------------------------------------------------------------
__global__ __launch_bounds__(256, 8) void k_scores_ct(const float* __restrict__ prev,
                                                      const float* __restrict__ q,
                                                      float* __restrict__ out_np,
                                                      float* __restrict__ ws_m,
                                                      float* __restrict__ ws_l,
                                                      float* __restrict__ ws_ct) {
    const int tid  = threadIdx.x;
    const int lane = tid & 63;
    const int wid  = tid >> 6;
    const int c    = blockIdx.x;                 // chunk 0..127
    const int b    = blockIdx.y;                 // 0..63
    const int t    = c * TCB + wid;              // this wave's row

    __shared__ float srow[WPB][TWOH];            // 16 KB, wave-private rows
    __shared__ float sscore[WPB];

    // 1) DMA this wave's row into its LDS region (no VGPR destinations)
    const float* gbase = prev + ((size_t)b * TT + t) * TWOH;
    #pragma unroll
    for (int j = 0; j < 4; ++j)
        gload_lds16(gbase + j * 256 + lane * 4, &srow[wid][j * 256]);

    // 2) q[b] lane-slice (single pre-reduced read; L2-hot)
    const vfloat4* __restrict__ qv = (const vfloat4*)(q + (size_t)b * TWOH);
    const vfloat4 q0 = qv[lane];
    const vfloat4 q1 = qv[64 + lane];
    const vfloat4 q2 = qv[128 + lane];
    const vfloat4 q3 = qv[192 + lane];

    // DMA completion tracked by this wave's vmcnt only.
    asm volatile("s_waitcnt vmcnt(0)" ::: "memory");
    __builtin_amdgcn_sched_barrier(0);

    // 3) copy-store + dot partials from LDS
    const vfloat4* sr = (const vfloat4*)&srow[wid][0];
    vfloat4* __restrict__ nprow =
        (vfloat4*)(out_np + (size_t)b * NP_STRIDE + (size_t)t * TWOH) + lane;
    const vfloat4 v0 = sr[lane];
    const vfloat4 v1 = sr[64 + lane];
    const vfloat4 v2 = sr[128 + lane];
    const vfloat4 v3 = sr[192 + lane];
    nprow[0]   = v0;
    nprow[64]  = v1;
    nprow[128] = v2;
    nprow[192] = v3;
    float d0 = v0.x * q0.x; d0 = fmaf(v0.y, q0.y, d0);
    d0 = fmaf(v0.z, q0.z, d0); d0 = fmaf(v0.w, q0.w, d0);
    float d1 = v1.x * q1.x; d1 = fmaf(v1.y, q1.y, d1);
    d1 = fmaf(v1.z, q1.z, d1); d1 = fmaf(v1.w, q1.w, d1);
    float d2 = v2.x * q2.x; d2 = fmaf(v2.y, q2.y, d2);
    d2 = fmaf(v2.z, q2.z, d2); d2 = fmaf(v2.w, q2.w, d2);
    float d3 = v3.x * q3.x; d3 = fmaf(v3.y, q3.y, d3);
    d3 = fmaf(v3.z, q3.z, d3); d3 = fmaf(v3.w, q3.w, d3);
    float pd = (d0 + d1) + (d2 + d3);
    #pragma unroll
    for (int off = 32; off > 0; off >>= 1)
        pd += __shfl_xor(pd, off, 64);
    if (lane == 0) sscore[wid] = pd;
    __syncthreads();

    // 4) block softmax over the 4 wave-uniform scores
    const float s0 = sscore[0], s1 = sscore[1], s2 = sscore[2], s3 = sscore[3];
    const float M  = fmaxf(fmaxf(s0, s1), fmaxf(s2, s3));
    const float a0 = __expf(s0 - M);
    const float a1 = __expf(s1 - M);
    const float a2 = __expf(s2 - M);
    const float a3 = __expf(s3 - M);
    const float L  = (a0 + a1) + (a2 + a3);

    // 5) weighted combine of the 4 rows; thread tid owns float4 index tid
    const vfloat4 x0 = ((const vfloat4*)&srow[0][0])[tid];
    const vfloat4 x1 = ((const vfloat4*)&srow[1][0])[tid];
    const vfloat4 x2 = ((const vfloat4*)&srow[2][0])[tid];
    const vfloat4 x3 = ((const vfloat4*)&srow[3][0])[tid];
    vfloat4 o;
    o.x = fmaf(a3, x3.x, fmaf(a2, x2.x, fmaf(a1, x1.x, a0 * x0.x)));
    o.y = fmaf(a3, x3.y, fmaf(a2, x2.y, fmaf(a1, x1.y, a0 * x0.y)));
    o.z = fmaf(a3, x3.z, fmaf(a2, x2.z, fmaf(a1, x1.z, a0 * x0.z)));
    o.w = fmaf(a3, x3.w, fmaf(a2, x2.w, fmaf(a1, x1.w, a0 * x0.w)));
    ((vfloat4*)(ws_ct + ((size_t)b * NCHUNK + c) * TWOH))[tid] = o;
    if (tid == 0) {
        ws_m[b * NCHUNK + c] = M;
        ws_l[b * NCHUNK + c] = L;
    }
}

// -------------------------------------------------------------------------
// K3: combine NCHUNK=128 chunk partials per b; also new_prev[b,512,:] = h[b,:].
// Single fused loop: coef computed once, feeds both L and the ct accumulate.
// grid = (4 e-chunks, 64 b) = 256 blocks; thread owns one e.
// -------------------------------------------------------------------------
__global__ __launch_bounds__(256) void k_finalize(const float* __restrict__ h,
                                                  const float* __restrict__ ws_m,
                                                  const float* __restrict__ ws_l,
                                                  const float* __restrict__ ws_ct,
                                                  float* __restrict__ out_ct,
                                                  float* __restrict__ out_np) {
    const int tid = threadIdx.x;
    const int e   = blockIdx.x * 256 + tid;
    const int b   = blockIdx.y;

    const float* __restrict__ wm = ws_m + b * NCHUNK;
    const float* __restrict__ wl = ws_l + b * NCHUNK;

    float M = -INFINITY;
    #pragma unroll 32
    for (int i = 0; i < NCHUNK; ++i) M = fmaxf(M, wm[i]);

    const float* __restrict__ cp = ws_ct + (size_t)b * NCHUNK * TWOH + e;
    float L = 0.f;
    float acc = 0.f;
    #pragma unroll 32
    for (int i = 0; i < NCHUNK; ++i) {
        const float ce = __expf(wm[i] - M);
        L   = fmaf(ce, wl[i], L);
        acc = fmaf(ce, cp[(size_t)i * TWOH], acc);
    }
    out_ct[b * TWOH + e] = acc * (1.0f / L);

    // concat row: new_prev[b, T, :] = h[b, :]
    out_np[(size_t)b * NP_STRIDE + (size_t)TT * TWOH + e] = h[b * TWOH + e];
}

extern "C" void kernel_launch(void* const* d_in, const int* in_sizes, int n_in,
                              void* d_out, int out_size, void* d_ws, size_t ws_size,
                              hipStream_t stream) {
    const float* h    = (const float*)d_in[0];   // (64, 1024)
    const float* prev = (const float*)d_in[1];   // (64, 512, 1024)
    const float* W    = (const float*)d_in[2];   // (1, 1024, 1024)
    float* out    = (float*)d_out;
    float* out_ct = out;                         // (64, 1024)
    float* out_np = out + BB * TWOH;             // (64, 513, 1024)

    // ws layout (floats):
    //   qpart[4*64*1024] | q[64*1024] | m[64*128] | l[64*128] | ct[64*128*1024]
    // total ~= 35 MB (harness ws observed ~512 MB from fill evidence).
    float* qpart = (float*)d_ws;
    float* qred  = qpart + KSPLIT * BB * TWOH;
    float* wsm   = qred + BB * TWOH;
    float* wsl   = wsm + BB * NCHUNK;
    float* wsc   = wsl + BB * NCHUNK;

    k_qgemm<<<dim3(4, BB, KSPLIT), 256, 0, stream>>>(h, W, qpart);
    k_qreduce<<<dim3(BB), 256, 0, stream>>>(qpart, qred);
    k_scores_ct<<<dim3(NCHUNK, BB), 256, 0, stream>>>(prev, qred, out_np, wsm, wsl, wsc);
    k_finalize<<<dim3(4, BB), 256, 0, stream>>>(h, wsm, wsl, wsc, out_ct, out_np);
}